// Round 2
// baseline (627.275 us; speedup 1.0000x reference)
//
#include <hip/hip_runtime.h>
#include <hip/hip_bf16.h>

// ---------------------------------------------------------------------------
// SparseLinear: y = spmm(COO, x^T)^T + bias
// R5: non-temporal hints on all streaming traffic (x, y, out, edge stream,
//     index reads) to keep xT (51 MB, 32x reuse) resident in Infinity Cache.
//     spmm inner loop reverted to R3 2-deep form (VGPR 20, occ 75%).
//     Numerics bit-identical to R3/R4 (same RNE rounding, same FMA order).
// ---------------------------------------------------------------------------

typedef float  f32x4 __attribute__((ext_vector_type(4)));
typedef unsigned int u32x4 __attribute__((ext_vector_type(4)));

// x (rows, cols) fp32 -> out (cols, rows) bf16. 64x64 tile, block = 256.
__global__ __launch_bounds__(256) void transpose_bf16_v2(
        const float* __restrict__ in,
        __hip_bfloat16* __restrict__ out,
        int rows, int cols) {
    // [col_local][row_local]; row stride 72 ushorts = 144 B (odd multiple of
    // 16 B -> conflict-free uint4 reads in store phase)
    __shared__ __hip_bfloat16 T[64][72];
    const int t  = threadIdx.x;
    const int c0 = blockIdx.x * 64;   // over cols
    const int r0 = blockIdx.y * 64;   // over rows

    {   // load phase: nt float4 per lane (x is read-once; keep out of L3)
        const int tx = t & 15, ty = t >> 4;
        const int c = c0 + tx * 4;
        for (int p = 0; p < 4; ++p) {
            const int rl = ty + p * 16;
            const int r = r0 + rl;
            float fx = 0.f, fy = 0.f, fz = 0.f, fw = 0.f;
            if (r < rows && c + 3 < cols) {
                f32x4 f = __builtin_nontemporal_load(
                    (const f32x4*)(in + (size_t)r * cols + c));
                fx = f.x; fy = f.y; fz = f.z; fw = f.w;
            } else if (r < rows) {
                const float* p0 = in + (size_t)r * cols;
                if (c + 0 < cols) fx = p0[c + 0];
                if (c + 1 < cols) fy = p0[c + 1];
                if (c + 2 < cols) fz = p0[c + 2];
                if (c + 3 < cols) fw = p0[c + 3];
            }
            T[tx * 4 + 0][rl] = __float2bfloat16(fx);
            T[tx * 4 + 1][rl] = __float2bfloat16(fy);
            T[tx * 4 + 2][rl] = __float2bfloat16(fz);
            T[tx * 4 + 3][rl] = __float2bfloat16(fw);
        }
    }
    __syncthreads();
    {   // store phase: uint4 = 8 bf16 per lane; NORMAL stores (xT wants L3)
        const int cl0 = t >> 3;   // 0..31
        const int rq  = t & 7;    // 0..7
        const int rl  = rq * 8;
        const int r   = r0 + rl;
        for (int q = 0; q < 2; ++q) {
            const int cl = q * 32 + cl0;
            const int c  = c0 + cl;
            if (c < cols) {
                if (r + 7 < rows) {
                    *(uint4*)(out + (size_t)c * rows + r) =
                        *(const uint4*)&T[cl][rl];
                } else {
                    for (int j = 0; j < 8 && r + j < rows; ++j)
                        out[(size_t)c * rows + r + j] = T[cl][rl + j];
                }
            }
        }
    }
}

// in (rows, cols) fp32 -> out (cols, rows) fp32. 64x64 tile, block = 256.
// Both sides streaming -> nt on loads and stores.
__global__ __launch_bounds__(256) void transpose32_v2(
        const float* __restrict__ in,
        float* __restrict__ out,
        int rows, int cols) {
    // row stride 68 floats = 272 B (odd multiple of 16 B)
    __shared__ float T[64][68];
    const int t  = threadIdx.x;
    const int c0 = blockIdx.x * 64;   // over cols
    const int r0 = blockIdx.y * 64;   // over rows

    {   // load: nt float4 per lane
        const int tx = t & 15, ty = t >> 4;
        const int c = c0 + tx * 4;
        for (int p = 0; p < 4; ++p) {
            const int rl = ty + p * 16;
            const int r = r0 + rl;
            float fx = 0.f, fy = 0.f, fz = 0.f, fw = 0.f;
            if (r < rows && c + 3 < cols) {
                f32x4 f = __builtin_nontemporal_load(
                    (const f32x4*)(in + (size_t)r * cols + c));
                fx = f.x; fy = f.y; fz = f.z; fw = f.w;
            } else if (r < rows) {
                const float* p0 = in + (size_t)r * cols;
                if (c + 0 < cols) fx = p0[c + 0];
                if (c + 1 < cols) fy = p0[c + 1];
                if (c + 2 < cols) fz = p0[c + 2];
                if (c + 3 < cols) fw = p0[c + 3];
            }
            T[tx * 4 + 0][rl] = fx;
            T[tx * 4 + 1][rl] = fy;
            T[tx * 4 + 2][rl] = fz;
            T[tx * 4 + 3][rl] = fw;
        }
    }
    __syncthreads();
    {   // store: nt float4 per lane
        const int rq  = t & 15;   // float4 over r
        const int cl0 = t >> 4;   // 0..15
        const int rl  = rq * 4;
        const int r   = r0 + rl;
        for (int p = 0; p < 4; ++p) {
            const int cl = p * 16 + cl0;
            const int c  = c0 + cl;
            if (c < cols) {
                if (r + 3 < rows) {
                    f32x4 f;
                    f.x = T[cl][rl + 0]; f.y = T[cl][rl + 1];
                    f.z = T[cl][rl + 2]; f.w = T[cl][rl + 3];
                    __builtin_nontemporal_store(
                        f, (f32x4*)(out + (size_t)c * rows + r));
                } else {
                    for (int j = 0; j < 4 && r + j < rows; ++j)
                        out[(size_t)c * rows + r + j] = T[cl][rl + j];
                }
            }
        }
    }
}

__global__ void zero_i32_kernel(int* __restrict__ p, int n) {
    int i = blockIdx.x * blockDim.x + threadIdx.x;
    if (i < n) p[i] = 0;
}

__global__ void hist_kernel(const int* __restrict__ rows, int nnz,
                            int* __restrict__ counts) {
    int e = blockIdx.x * blockDim.x + threadIdx.x;
    if (e < nnz) {
        int r = __builtin_nontemporal_load(rows + e);
        atomicAdd(&counts[r], 1);
    }
}

// ---- hierarchical exclusive scan of counts[0..n) into offsets[0..n] --------
#define SCAN_T 256
#define SCAN_CHUNK 2048

__global__ __launch_bounds__(SCAN_T) void scan1_kernel(
        const int* __restrict__ counts, int* __restrict__ offsets,
        int* __restrict__ bsum, int n) {
    __shared__ int sdata[SCAN_T];
    int t = threadIdx.x;
    int base_i = blockIdx.x * SCAN_CHUNK + t * 8;
    int vals[8];
    int tot = 0;
#pragma unroll
    for (int j = 0; j < 8; ++j) {
        int i = base_i + j;
        int v = (i < n) ? counts[i] : 0;
        tot += v;
        vals[j] = tot;
    }
    sdata[t] = tot;
    __syncthreads();
    for (int off = 1; off < SCAN_T; off <<= 1) {
        int x = (t >= off) ? sdata[t - off] : 0;
        __syncthreads();
        sdata[t] += x;
        __syncthreads();
    }
    int tbase = (t > 0) ? sdata[t - 1] : 0;
#pragma unroll
    for (int j = 0; j < 8; ++j) {
        int i = base_i + j;
        if (i < n) offsets[i + 1] = tbase + vals[j];
    }
    if (t == SCAN_T - 1) bsum[blockIdx.x] = sdata[SCAN_T - 1];
}

__global__ void scan2_kernel(int* __restrict__ bsum, int nb) {
    if (threadIdx.x == 0 && blockIdx.x == 0) {
        int run = 0;
        for (int i = 0; i < nb; ++i) { int v = bsum[i]; bsum[i] = run; run += v; }
    }
}

__global__ void scan3_kernel(int* __restrict__ offsets,
                             const int* __restrict__ bsum, int n) {
    int i = blockIdx.x * blockDim.x + threadIdx.x;
    if (i == 0) offsets[0] = 0;
    if (i < n) offsets[i + 1] += bsum[i / SCAN_CHUNK];
}

// counting-sort scatter; packs (col, val-bits) into one int2 stream.
// Index/value reads are read-once -> nt. edges writes stay cached (read by
// spmm next).
__global__ void scatter_kernel(const int* __restrict__ rows,
                               const int* __restrict__ cols,
                               const float* __restrict__ vals, int nnz,
                               const int* __restrict__ offsets,
                               int* __restrict__ counts,
                               int2* __restrict__ edges) {
    int e = blockIdx.x * blockDim.x + threadIdx.x;
    if (e < nnz) {
        int r = __builtin_nontemporal_load(rows + e);
        int c = __builtin_nontemporal_load(cols + e);
        float v = __builtin_nontemporal_load(vals + e);
        int p = offsets[r] + atomicSub(&counts[r], 1) - 1;
        edges[p] = make_int2(c, __float_as_int(v));
    }
}

__device__ __forceinline__ float bf_lo(unsigned u) {
    return __uint_as_float(u << 16);
}
__device__ __forceinline__ float bf_hi(unsigned u) {
    return __uint_as_float(u & 0xffff0000u);
}

// wave-per-row spmm: block = 256 threads = 4 waves = 4 rows; lane covers
// 8 batch elems via one 16-B bf16x8 gather per edge. No barriers.
// R5: R3 2-deep loop; edge stream nt-loaded; y nt-stored; xT gathers cached.
__global__ __launch_bounds__(256) void spmm_kernel(
        const ushort* __restrict__ xT,       // bf16 (IN, B)
        const int* __restrict__ offsets,     // OUT+1
        const int2* __restrict__ edges,      // (col, val-bits), row-sorted
        const float* __restrict__ bias,      // OUT
        float* __restrict__ y,               // (OUT, B) fp32
        int B, int OUTn) {
    const int lane = threadIdx.x & 63;
    const int r = blockIdx.x * 4 + (threadIdx.x >> 6);
    if (r >= OUTn) return;
    const int e0 = offsets[r];
    const int e1 = offsets[r + 1];
    const float bv = bias[r];
    const ushort* xb = xT + (size_t)(lane << 3);   // 8 batch per lane

    float a0 = 0.f, a1 = 0.f, a2 = 0.f, a3 = 0.f;
    float a4 = 0.f, a5 = 0.f, a6 = 0.f, a7 = 0.f;

    int e = e0;
    for (; e + 2 <= e1; e += 2) {
        const long long p0 =
            __builtin_nontemporal_load((const long long*)(edges + e));
        const long long p1 =
            __builtin_nontemporal_load((const long long*)(edges + e + 1));
        const int   c0 = (int)(unsigned)p0;
        const float v0 = __int_as_float((int)(p0 >> 32));
        const int   c1 = (int)(unsigned)p1;
        const float v1 = __int_as_float((int)(p1 >> 32));
        const uint4 u0 = *(const uint4*)(xb + (size_t)c0 * B);
        const uint4 u1 = *(const uint4*)(xb + (size_t)c1 * B);
        a0 += v0 * bf_lo(u0.x); a1 += v0 * bf_hi(u0.x);
        a2 += v0 * bf_lo(u0.y); a3 += v0 * bf_hi(u0.y);
        a4 += v0 * bf_lo(u0.z); a5 += v0 * bf_hi(u0.z);
        a6 += v0 * bf_lo(u0.w); a7 += v0 * bf_hi(u0.w);
        a0 += v1 * bf_lo(u1.x); a1 += v1 * bf_hi(u1.x);
        a2 += v1 * bf_lo(u1.y); a3 += v1 * bf_hi(u1.y);
        a4 += v1 * bf_lo(u1.z); a5 += v1 * bf_hi(u1.z);
        a6 += v1 * bf_lo(u1.w); a7 += v1 * bf_hi(u1.w);
    }
    if (e < e1) {
        const long long p0 =
            __builtin_nontemporal_load((const long long*)(edges + e));
        const int   c0 = (int)(unsigned)p0;
        const float v0 = __int_as_float((int)(p0 >> 32));
        const uint4 u0 = *(const uint4*)(xb + (size_t)c0 * B);
        a0 += v0 * bf_lo(u0.x); a1 += v0 * bf_hi(u0.x);
        a2 += v0 * bf_lo(u0.y); a3 += v0 * bf_hi(u0.y);
        a4 += v0 * bf_lo(u0.z); a5 += v0 * bf_hi(u0.z);
        a6 += v0 * bf_lo(u0.w); a7 += v0 * bf_hi(u0.w);
    }

    float* yp = y + (size_t)r * B + (size_t)(lane << 3);
    f32x4 o0, o1;
    o0.x = a0 + bv; o0.y = a1 + bv; o0.z = a2 + bv; o0.w = a3 + bv;
    o1.x = a4 + bv; o1.y = a5 + bv; o1.z = a6 + bv; o1.w = a7 + bv;
    __builtin_nontemporal_store(o0, (f32x4*)(yp));
    __builtin_nontemporal_store(o1, (f32x4*)(yp + 4));
}

extern "C" void kernel_launch(void* const* d_in, const int* in_sizes, int n_in,
                              void* d_out, int out_size, void* d_ws, size_t ws_size,
                              hipStream_t stream) {
    const float* x       = (const float*)d_in[0];   // (B, IN)
    const int*   indices = (const int*)  d_in[1];   // [2, NNZ]
    const float* values  = (const float*)d_in[2];   // NNZ
    const float* bias    = (const float*)d_in[3];   // OUT

    float* out = (float*)d_out;

    const int NNZ = in_sizes[2];
    const int OUT = in_sizes[3];
    const int B   = out_size / OUT;
    const int IN  = (int)((size_t)in_sizes[0] / (size_t)B);

    const int* rows = indices;
    const int* cols = indices + NNZ;

    // workspace layout (section sizes are 16B multiples for the shapes in play)
    char* ws = (char*)d_ws;
    __hip_bfloat16* xT = (__hip_bfloat16*)ws;  ws += (size_t)IN * B * sizeof(__hip_bfloat16);
    float* y       = (float*)ws;  ws += (size_t)OUT * B * sizeof(float);
    int2*  edges   = (int2*)ws;   ws += (size_t)NNZ * sizeof(int2);
    int*   counts  = (int*)ws;    ws += (size_t)OUT * sizeof(int);
    int*   offsets = (int*)ws;    ws += (size_t)(OUT + 1) * sizeof(int);
    int*   bsum    = (int*)ws;    ws += 256 * sizeof(int);

    const int nchunks = (OUT + SCAN_CHUNK - 1) / SCAN_CHUNK;

    // 1) x (B,IN) fp32 -> xT (IN,B) bf16 (vectorized 64x64 transpose)
    transpose_bf16_v2<<<dim3((IN + 63) / 64, (B + 63) / 64), 256, 0, stream>>>(
        x, xT, B, IN);

    // 2) CSR build: histogram -> hierarchical scan -> packed scatter
    zero_i32_kernel<<<(OUT + 255) / 256, 256, 0, stream>>>(counts, OUT);
    hist_kernel<<<(NNZ + 255) / 256, 256, 0, stream>>>(rows, NNZ, counts);
    scan1_kernel<<<nchunks, SCAN_T, 0, stream>>>(counts, offsets, bsum, OUT);
    scan2_kernel<<<1, 64, 0, stream>>>(bsum, nchunks);
    scan3_kernel<<<(OUT + 255) / 256, 256, 0, stream>>>(offsets, bsum, OUT);
    scatter_kernel<<<(NNZ + 255) / 256, 256, 0, stream>>>(
        rows, cols, values, NNZ, offsets, counts, edges);

    // 3) heavy phase: wave-per-row, bf16x8 gathers; xT cached, streams nt
    spmm_kernel<<<(OUT + 3) / 4, 256, 0, stream>>>(
        (const ushort*)xT, offsets, edges, bias, y, B, OUT);

    // 4) y (OUT,B) -> out (B,OUT) (vectorized 64x64 transpose, all nt)
    transpose32_v2<<<dim3((B + 63) / 64, (OUT + 63) / 64), 256, 0, stream>>>(
        y, out, OUT, B);
}